// Round 11
// baseline (1000.724 us; speedup 1.0000x reference)
//
#include <hip/hip_runtime.h>
#include <hip/hip_bf16.h>

#define Vn 25000
#define En 100000
#define NODE_IN 74
#define EDGE_IN 12
#define OUTD 64
#define EHID 128
#define NUM_STEPS 6

#define EPB 64    // edges per block
#define HPAD 68   // h_t row pitch (f16 elements)

typedef __attribute__((ext_vector_type(8))) _Float16 half8;
typedef __attribute__((ext_vector_type(16))) float floatx16;

// h[v,o] = relu(node[v,:] @ Wp + bp)   [V,74]@[74,64]  (all fp32)
__global__ void proj_kernel(const float* __restrict__ node,
                            const float* __restrict__ Wp,
                            const float* __restrict__ bp,
                            float* __restrict__ h) {
  __shared__ float nf[NODE_IN];
  int v = blockIdx.x;
  int o = threadIdx.x;  // 64
  for (int i = o; i < NODE_IN; i += 64) nf[i] = node[(size_t)v * NODE_IN + i];
  __syncthreads();
  float acc = bp[o];
  for (int i = 0; i < NODE_IN; ++i) acc = fmaf(nf[i], Wp[i * OUTD + o], acc);
  h[(size_t)v * OUTD + o] = fmaxf(acc, 0.0f);
}

// f[e,k] = relu(edge[e,:] @ We1 + be1)   [E,12]@[12,128] fp32, stored f16
__global__ void edge_kernel(const float* __restrict__ ef,
                            const float* __restrict__ We1,
                            const float* __restrict__ be1,
                            _Float16* __restrict__ f) {
  __shared__ float es[EDGE_IN];
  int e = blockIdx.x;
  int k = threadIdx.x;  // 128
  if (k < EDGE_IN) es[k] = ef[(size_t)e * EDGE_IN + k];
  __syncthreads();
  float acc = be1[k];
  for (int j = 0; j < EDGE_IN; ++j) acc = fmaf(es[j], We1[j * EHID + k], acc);
  f[(size_t)e * EHID + k] = (_Float16)fmaxf(acc, 0.0f);
}

// B layout for 32x32x16_f16 (same as R8, proven correct):
//   g = (((i*2 + c)*8 + s)*64 + lane)*8 + j
// holds f16(We2[k = s*16 + 8*(lane>>5) + j][col = i*64 + c*32 + (lane&31)]).
__global__ void w2r_kernel(const float* __restrict__ We2,
                           _Float16* __restrict__ w2s) {
  int g = blockIdx.x * 256 + threadIdx.x;  // < 524288
  int j = g & 7;
  int lane = (g >> 3) & 63;
  int s = (g >> 9) & 7;
  int c = (g >> 12) & 1;
  int i = g >> 13;
  int k = s * 16 + 8 * (lane >> 5) + j;
  int col = i * 64 + c * 32 + (lane & 31);
  w2s[g] = (_Float16)We2[(size_t)k * (OUTD * OUTD) + col];
}

// Fused per-step message kernel: 64 edges/block, 512 threads = 8 waves,
// wave = (edge-half, col-half, K-half). K-split halves per-wave register
// state (A 16, B ping-pong 32, acc 16) -> ~2x resident waves.
// K-half partials combined in LDS before one atomicAdd per (dst,col).
__global__ __launch_bounds__(512) void msg_kernel(
    const float* __restrict__ h,
    const _Float16* __restrict__ f,
    const _Float16* __restrict__ w2s,
    const int* __restrict__ src,
    const int* __restrict__ dst,
    const float* __restrict__ be2,
    float* __restrict__ agg) {
  __shared__ _Float16 h_t[64 * HPAD];  // [i][e_local], f16 (8.7 KB)
  __shared__ float accbuf[4 * 1024];   // kh=1 partials (16 KB)
  __shared__ int s_dst[EPB];

  const int tid = threadIdx.x;
  const int wvq = tid >> 6;        // wave 0..7
  const int eh = (wvq >> 2) & 1;   // edge half (32 edges)
  const int ch = (wvq >> 1) & 1;   // col half (32 outputs)
  const int kh = wvq & 1;          // K half (64 of 128)
  const int lane = tid & 63;
  const int l31 = lane & 31;
  const int lh = lane >> 5;        // k-sub selector within fragments
  const int e0 = blockIdx.x * EPB;

  if (tid < EPB) {
    int e = e0 + tid;
    s_dst[tid] = (e < En) ? dst[e] : -1;
  }
  {
    int e = tid & 63;
    int ib = tid >> 6;  // i-block 0..7 (8 i's each)
    int eg = e0 + e;
    int sv = (eg < En) ? src[eg] : 0;
    const float4* hp = reinterpret_cast<const float4*>(h + (size_t)sv * OUTD + ib * 8);
    for (int cc = 0; cc < 2; ++cc) {
      float4 val = hp[cc];
      int i4 = ib * 8 + cc * 4;
      h_t[(i4 + 0) * HPAD + e] = (_Float16)val.x;
      h_t[(i4 + 1) * HPAD + e] = (_Float16)val.y;
      h_t[(i4 + 2) * HPAD + e] = (_Float16)val.z;
      h_t[(i4 + 3) * HPAD + e] = (_Float16)val.w;
    }
  }
  __syncthreads();

  // A-fragments (f16): lane's edge row, this wave's K-half (4 k-steps of 16).
  // A[m=l31][k = (4*kh+s)*16 + 8*lh + j]
  half8 afr[4];
  {
    int e = e0 + eh * 32 + l31;
    if (e >= En) e = En - 1;  // clamped rows suppressed at scatter
    const _Float16* fr = f + (size_t)e * EHID + kh * 64 + 8 * lh;
    for (int s = 0; s < 4; ++s)
      afr[s] = *reinterpret_cast<const half8*>(fr + s * 16);
  }

  // per-wave/lane base into the B layout: (ch, kh) selects a contiguous 2 KB
  // slice of each 16 KB i-tile.
  const _Float16* w2b = w2s + ch * 4096 + kh * 2048 + lane * 8;

#define LOADB(dstv, ii)                                                     \
  {                                                                         \
    const _Float16* p_ = w2b + (size_t)(ii) * 8192;                         \
    dstv[0] = *reinterpret_cast<const half8*>(p_);                          \
    dstv[1] = *reinterpret_cast<const half8*>(p_ + 512);                    \
    dstv[2] = *reinterpret_cast<const half8*>(p_ + 1024);                   \
    dstv[3] = *reinterpret_cast<const half8*>(p_ + 1536);                   \
  }

  floatx16 acc = (floatx16){0.f};

  half8 ba[4], bb[4];
  LOADB(ba, 0);
  LOADB(bb, 1);

#define BODY(iv, breg)                                                        \
  {                                                                           \
    _Float16 hh = h_t[(iv) * HPAD + eh * 32 + l31];                           \
    half8 hb = (half8){hh, hh, hh, hh, hh, hh, hh, hh};                       \
    for (int s = 0; s < 4; ++s) {                                             \
      half8 as = afr[s] * hb;                                                 \
      acc = __builtin_amdgcn_mfma_f32_32x32x16_f16(as, breg[s], acc, 0, 0, 0); \
    }                                                                         \
  }

  for (int ii = 0; ii < 32; ++ii) {
    int i0 = 2 * ii;
    BODY(i0, ba);
    {
      int inx = (i0 + 2 < 64) ? i0 + 2 : 63;
      LOADB(ba, inx);
    }
    BODY(i0 + 1, bb);
    {
      int inx = (i0 + 3 < 64) ? i0 + 3 : 63;
      LOADB(bb, inx);
    }
  }

  // be2 contribution (exact 0 here): kh==0 waves add sum_i h[src,i]*be2[i*64+o]
  if (kh == 0) {
    for (int s = 0; s < 4; ++s) {
      half8 ha, b2;
      for (int j = 0; j < 8; ++j) {
        int i = s * 16 + 8 * lh + j;
        ha[j] = h_t[i * HPAD + eh * 32 + l31];
        b2[j] = (_Float16)be2[i * 64 + ch * 32 + l31];
      }
      acc = __builtin_amdgcn_mfma_f32_32x32x16_f16(ha, b2, acc, 0, 0, 0);
    }
  }

  // combine K-halves through LDS: kh=1 writes partials, kh=0 adds + scatters.
  {
    float* ab = &accbuf[(eh * 2 + ch) * 1024];
    if (kh == 1) {
      for (int reg = 0; reg < 16; ++reg) ab[reg * 64 + lane] = acc[reg];
    }
  }
  __syncthreads();
  if (kh == 0) {
    const float* ab = &accbuf[(eh * 2 + ch) * 1024];
    int col = ch * 32 + l31;
    for (int reg = 0; reg < 16; ++reg) {
      float v = acc[reg] + ab[reg * 64 + lane];
      int r = (reg & 3) + 8 * (reg >> 2) + 4 * lh;
      int d = s_dst[eh * 32 + r];
      if (d >= 0) atomicAdd(&agg[(size_t)d * OUTD + col], v);
    }
  }
}

// h_out = relu(agg + bias); re-zero agg; last step also writes fp32 d_out
__global__ void update_kernel(float* __restrict__ agg,
                              const float* __restrict__ bias,
                              float* __restrict__ hout,
                              float* __restrict__ dout, int last) {
  int g = blockIdx.x * 256 + threadIdx.x;
  if (g >= Vn * OUTD) return;
  float v = agg[g];
  agg[g] = 0.0f;
  float r = fmaxf(v + bias[g & 63], 0.0f);
  hout[g] = r;
  if (last) dout[g] = r;
}

extern "C" void kernel_launch(void* const* d_in, const int* in_sizes, int n_in,
                              void* d_out, int out_size, void* d_ws, size_t ws_size,
                              hipStream_t stream) {
  const float* node = (const float*)d_in[0];
  const float* edge = (const float*)d_in[1];
  const int* src = (const int*)d_in[2];
  const int* dst = (const int*)d_in[3];
  const float* Wp   = (const float*)d_in[4];
  const float* bp   = (const float*)d_in[5];
  const float* We1  = (const float*)d_in[6];
  const float* be1  = (const float*)d_in[7];
  const float* We2  = (const float*)d_in[8];
  const float* be2  = (const float*)d_in[9];
  const float* bias = (const float*)d_in[10];
  float* out = (float*)d_out;

  char* ws = (char*)d_ws;
  float* agg = (float*)(ws);                        // 6,400,000 B
  float* h_a = (float*)(ws + 6400000);              // 6,400,000 B
  float* h_b = (float*)(ws + 12800000);             // 6,400,000 B
  _Float16* f   = (_Float16*)(ws + 19200000);       // 25,600,000 B
  _Float16* w2s = (_Float16*)(ws + 44800000);       // 1,048,576 B

  hipMemsetAsync(agg, 0, (size_t)Vn * OUTD * sizeof(float), stream);
  proj_kernel<<<Vn, 64, 0, stream>>>(node, Wp, bp, h_a);
  edge_kernel<<<En, 128, 0, stream>>>(edge, We1, be1, f);
  w2r_kernel<<<(OUTD * OUTD * EHID) / 256, 256, 0, stream>>>(We2, w2s);

  float* hin = h_a;
  float* hout = h_b;
  for (int s = 0; s < NUM_STEPS; ++s) {
    msg_kernel<<<(En + EPB - 1) / EPB, 512, 0, stream>>>(hin, f, w2s, src, dst, be2, agg);
    update_kernel<<<(Vn * OUTD + 255) / 256, 256, 0, stream>>>(
        agg, bias, hout, out, s == NUM_STEPS - 1);
    float* t = hin; hin = hout; hout = t;
  }
}

// Round 12
// 934.593 us; speedup vs baseline: 1.0708x; 1.0708x over previous
//
#include <hip/hip_runtime.h>
#include <hip/hip_bf16.h>

#define Vn 25000
#define En 100000
#define NODE_IN 74
#define EDGE_IN 12
#define OUTD 64
#define EHID 128
#define NUM_STEPS 6

#define EPB 128   // edges per block: 4 tiles of 32 per wave
#define HPAD 132  // h_t row pitch (f16 elements)

typedef __attribute__((ext_vector_type(8))) _Float16 half8;
typedef __attribute__((ext_vector_type(16))) float floatx16;

// h[v,o] = relu(node[v,:] @ Wp + bp)   [V,74]@[74,64]  (all fp32)
__global__ void proj_kernel(const float* __restrict__ node,
                            const float* __restrict__ Wp,
                            const float* __restrict__ bp,
                            float* __restrict__ h) {
  __shared__ float nf[NODE_IN];
  int v = blockIdx.x;
  int o = threadIdx.x;  // 64
  for (int i = o; i < NODE_IN; i += 64) nf[i] = node[(size_t)v * NODE_IN + i];
  __syncthreads();
  float acc = bp[o];
  for (int i = 0; i < NODE_IN; ++i) acc = fmaf(nf[i], Wp[i * OUTD + o], acc);
  h[(size_t)v * OUTD + o] = fmaxf(acc, 0.0f);
}

// f[e,k] = relu(edge[e,:] @ We1 + be1)   [E,12]@[12,128] fp32, stored f16
__global__ void edge_kernel(const float* __restrict__ ef,
                            const float* __restrict__ We1,
                            const float* __restrict__ be1,
                            _Float16* __restrict__ f) {
  __shared__ float es[EDGE_IN];
  int e = blockIdx.x;
  int k = threadIdx.x;  // 128
  if (k < EDGE_IN) es[k] = ef[(size_t)e * EDGE_IN + k];
  __syncthreads();
  float acc = be1[k];
  for (int j = 0; j < EDGE_IN; ++j) acc = fmaf(es[j], We1[j * EHID + k], acc);
  f[(size_t)e * EHID + k] = (_Float16)fmaxf(acc, 0.0f);
}

// B layout for 32x32x16_f16 (proven since R8):
//   g = (((i*2 + c)*8 + s)*64 + lane)*8 + j
// holds f16(We2[k = s*16 + 8*(lane>>5) + j][col = i*64 + c*32 + (lane&31)]).
__global__ void w2r_kernel(const float* __restrict__ We2,
                           _Float16* __restrict__ w2s) {
  int g = blockIdx.x * 256 + threadIdx.x;  // < 524288
  int j = g & 7;
  int lane = (g >> 3) & 63;
  int s = (g >> 9) & 7;
  int c = (g >> 12) & 1;
  int i = g >> 13;
  int k = s * 16 + 8 * (lane >> 5) + j;
  int col = i * 64 + c * 32 + (lane & 31);
  w2s[g] = (_Float16)We2[(size_t)k * (OUTD * OUTD) + col];
}

// Fused per-step message kernel: 128 edges/block, 256 threads = 4 waves,
// wave = (kh, ch). Each wave: 4 edge-tiles x col-half x K-half.
// Per i: 4 B-frags (4 KB) shared across 16 MFMAs -> 256 B of B per MFMA
// (4x less operand traffic than all previous rounds). 4 independent
// accumulator chains. Both K-halves scatter via fp32 atomicAdd.
__global__ __launch_bounds__(256) void msg_kernel(
    const float* __restrict__ h,
    const _Float16* __restrict__ f,
    const _Float16* __restrict__ w2s,
    const int* __restrict__ src,
    const int* __restrict__ dst,
    const float* __restrict__ be2,
    float* __restrict__ agg) {
  __shared__ _Float16 h_t[64 * HPAD];  // [i][e_local], f16 (16.9 KB)
  __shared__ int s_dst[EPB];

  const int tid = threadIdx.x;
  const int wvq = tid >> 6;        // wave 0..3
  const int ch = wvq & 1;          // col half (32 outputs)
  const int kh = wvq >> 1;         // K half (64 of 128)
  const int lane = tid & 63;
  const int l31 = lane & 31;
  const int lh = lane >> 5;        // k-sub selector within fragments
  const int e0 = blockIdx.x * EPB;

  if (tid < EPB) {
    int e = e0 + tid;
    s_dst[tid] = (e < En) ? dst[e] : -1;
  }
  {
    int e = tid & 127;
    int ib = tid >> 7;  // i-half 0..1 (32 i's each)
    int eg = e0 + e;
    int sv = (eg < En) ? src[eg] : 0;
    const float4* hp = reinterpret_cast<const float4*>(h + (size_t)sv * OUTD + ib * 32);
    for (int cc = 0; cc < 8; ++cc) {
      float4 val = hp[cc];
      int i4 = ib * 32 + cc * 4;
      h_t[(i4 + 0) * HPAD + e] = (_Float16)val.x;
      h_t[(i4 + 1) * HPAD + e] = (_Float16)val.y;
      h_t[(i4 + 2) * HPAD + e] = (_Float16)val.z;
      h_t[(i4 + 3) * HPAD + e] = (_Float16)val.w;
    }
  }
  __syncthreads();

  // A-fragments (f16): 4 edge-tiles x 4 k-steps (this wave's K-half).
  // A[m=l31][k = kh*64 + s*16 + 8*lh + j]
  half8 afr[4][4];
  for (int t = 0; t < 4; ++t) {
    int e = e0 + t * 32 + l31;
    if (e >= En) e = En - 1;  // clamped rows suppressed at scatter
    const _Float16* fr = f + (size_t)e * EHID + kh * 64 + 8 * lh;
    for (int s = 0; s < 4; ++s)
      afr[t][s] = *reinterpret_cast<const half8*>(fr + s * 16);
  }

  // per-wave/lane base into the B layout: (ch,kh) = contiguous 2 KB slice/i.
  const _Float16* w2b = w2s + ch * 4096 + kh * 2048 + lane * 8;

#define LOADB(dstv, ii)                                                     \
  {                                                                         \
    const _Float16* p_ = w2b + (size_t)(ii) * 8192;                         \
    dstv[0] = *reinterpret_cast<const half8*>(p_);                          \
    dstv[1] = *reinterpret_cast<const half8*>(p_ + 512);                    \
    dstv[2] = *reinterpret_cast<const half8*>(p_ + 1024);                   \
    dstv[3] = *reinterpret_cast<const half8*>(p_ + 1536);                   \
  }

  floatx16 acc0 = (floatx16){0.f};
  floatx16 acc1 = (floatx16){0.f};
  floatx16 acc2 = (floatx16){0.f};
  floatx16 acc3 = (floatx16){0.f};

  half8 ba[4], bb[4];
  LOADB(ba, 0);
  LOADB(bb, 1);

  // Per i: 4 B-frags feed 16 MFMAs (4 tiles x 4 k-steps), 4 indep chains.
#define BODY(iv, breg)                                                          \
  {                                                                             \
    _Float16 h0 = h_t[(iv) * HPAD + 0 * 32 + l31];                              \
    _Float16 h1 = h_t[(iv) * HPAD + 1 * 32 + l31];                              \
    _Float16 h2 = h_t[(iv) * HPAD + 2 * 32 + l31];                              \
    _Float16 h3 = h_t[(iv) * HPAD + 3 * 32 + l31];                              \
    half8 hb0 = (half8){h0, h0, h0, h0, h0, h0, h0, h0};                        \
    half8 hb1 = (half8){h1, h1, h1, h1, h1, h1, h1, h1};                        \
    half8 hb2 = (half8){h2, h2, h2, h2, h2, h2, h2, h2};                        \
    half8 hb3 = (half8){h3, h3, h3, h3, h3, h3, h3, h3};                        \
    for (int s = 0; s < 4; ++s) {                                               \
      half8 a0 = afr[0][s] * hb0;                                               \
      half8 a1 = afr[1][s] * hb1;                                               \
      half8 a2 = afr[2][s] * hb2;                                               \
      half8 a3 = afr[3][s] * hb3;                                               \
      acc0 = __builtin_amdgcn_mfma_f32_32x32x16_f16(a0, breg[s], acc0, 0, 0, 0); \
      acc1 = __builtin_amdgcn_mfma_f32_32x32x16_f16(a1, breg[s], acc1, 0, 0, 0); \
      acc2 = __builtin_amdgcn_mfma_f32_32x32x16_f16(a2, breg[s], acc2, 0, 0, 0); \
      acc3 = __builtin_amdgcn_mfma_f32_32x32x16_f16(a3, breg[s], acc3, 0, 0, 0); \
    }                                                                           \
  }

  for (int ii = 0; ii < 32; ++ii) {
    int i0 = 2 * ii;
    BODY(i0, ba);
    {
      int inx = (i0 + 2 < 64) ? i0 + 2 : 63;
      LOADB(ba, inx);
    }
    BODY(i0 + 1, bb);
    {
      int inx = (i0 + 3 < 64) ? i0 + 3 : 63;
      LOADB(bb, inx);
    }
  }

  // be2 contribution (exact 0 here): kh==0 waves add sum_i h[src,i]*be2[i*64+o]
  if (kh == 0) {
    half8 b2[4];
    for (int s = 0; s < 4; ++s)
      for (int j = 0; j < 8; ++j)
        b2[s][j] = (_Float16)be2[(s * 16 + 8 * lh + j) * 64 + ch * 32 + l31];
    for (int s = 0; s < 4; ++s) {
      half8 ha0, ha1, ha2, ha3;
      for (int j = 0; j < 8; ++j) {
        int i = s * 16 + 8 * lh + j;
        ha0[j] = h_t[i * HPAD + 0 * 32 + l31];
        ha1[j] = h_t[i * HPAD + 1 * 32 + l31];
        ha2[j] = h_t[i * HPAD + 2 * 32 + l31];
        ha3[j] = h_t[i * HPAD + 3 * 32 + l31];
      }
      acc0 = __builtin_amdgcn_mfma_f32_32x32x16_f16(ha0, b2[s], acc0, 0, 0, 0);
      acc1 = __builtin_amdgcn_mfma_f32_32x32x16_f16(ha1, b2[s], acc1, 0, 0, 0);
      acc2 = __builtin_amdgcn_mfma_f32_32x32x16_f16(ha2, b2[s], acc2, 0, 0, 0);
      acc3 = __builtin_amdgcn_mfma_f32_32x32x16_f16(ha3, b2[s], acc3, 0, 0, 0);
    }
  }

  // scatter: C/D layout col=lane&31, row=(reg&3)+8*(reg>>2)+4*(lane>>5)
  int col = ch * 32 + l31;
  floatx16 accs[4] = {acc0, acc1, acc2, acc3};
  for (int t = 0; t < 4; ++t) {
    for (int reg = 0; reg < 16; ++reg) {
      int r = (reg & 3) + 8 * (reg >> 2) + 4 * lh;
      int d = s_dst[t * 32 + r];
      if (d >= 0) atomicAdd(&agg[(size_t)d * OUTD + col], accs[t][reg]);
    }
  }
}

// h_out = relu(agg + bias); re-zero agg; last step also writes fp32 d_out
__global__ void update_kernel(float* __restrict__ agg,
                              const float* __restrict__ bias,
                              float* __restrict__ hout,
                              float* __restrict__ dout, int last) {
  int g = blockIdx.x * 256 + threadIdx.x;
  if (g >= Vn * OUTD) return;
  float v = agg[g];
  agg[g] = 0.0f;
  float r = fmaxf(v + bias[g & 63], 0.0f);
  hout[g] = r;
  if (last) dout[g] = r;
}

extern "C" void kernel_launch(void* const* d_in, const int* in_sizes, int n_in,
                              void* d_out, int out_size, void* d_ws, size_t ws_size,
                              hipStream_t stream) {
  const float* node = (const float*)d_in[0];
  const float* edge = (const float*)d_in[1];
  const int* src = (const int*)d_in[2];
  const int* dst = (const int*)d_in[3];
  const float* Wp   = (const float*)d_in[4];
  const float* bp   = (const float*)d_in[5];
  const float* We1  = (const float*)d_in[6];
  const float* be1  = (const float*)d_in[7];
  const float* We2  = (const float*)d_in[8];
  const float* be2  = (const float*)d_in[9];
  const float* bias = (const float*)d_in[10];
  float* out = (float*)d_out;

  char* ws = (char*)d_ws;
  float* agg = (float*)(ws);                        // 6,400,000 B
  float* h_a = (float*)(ws + 6400000);              // 6,400,000 B
  float* h_b = (float*)(ws + 12800000);             // 6,400,000 B
  _Float16* f   = (_Float16*)(ws + 19200000);       // 25,600,000 B
  _Float16* w2s = (_Float16*)(ws + 44800000);       // 1,048,576 B

  hipMemsetAsync(agg, 0, (size_t)Vn * OUTD * sizeof(float), stream);
  proj_kernel<<<Vn, 64, 0, stream>>>(node, Wp, bp, h_a);
  edge_kernel<<<En, 128, 0, stream>>>(edge, We1, be1, f);
  w2r_kernel<<<(OUTD * OUTD * EHID) / 256, 256, 0, stream>>>(We2, w2s);

  float* hin = h_a;
  float* hout = h_b;
  for (int s = 0; s < NUM_STEPS; ++s) {
    msg_kernel<<<(En + EPB - 1) / EPB, 256, 0, stream>>>(hin, f, w2s, src, dst, be2, agg);
    update_kernel<<<(Vn * OUTD + 255) / 256, 256, 0, stream>>>(
        agg, bias, hout, out, s == NUM_STEPS - 1);
    float* t = hin; hin = hout; hout = t;
  }
}